// Round 3
// baseline (496.714 us; speedup 1.0000x reference)
//
#include <hip/hip_runtime.h>
#include <hip/hip_bf16.h>

// Transducer joint: logits[b,t,u,:] = tanh(enc_out[b,t,:] + pred_out[b,u,:]) @ W_out + b_out
// B=4 T=256 U=64 D=512 J=1024 V=1024.
// R4: vocab GEMM = 256x256/BK=32 8-wave deep pipeline (T1/T2/T3+T4/T5), 64KB static LDS.
//     Verified: bank conflicts 1.68e7 -> 0, FETCH 531->99MB, 243->184us.
// R5: (a) fuse tanh generation of the A-tile INTO the vocab GEMM (A-tile spans only
//     4 enc rows + 64 pred rows -> tiny L2-resident reads; tanh VALU hides under MFMA).
//     Kills tanh_mat kernel + 128MB joint write + 128MB joint read.
//     (b) collapse 9 dispatches -> 3 (prep / proj2 / vocab_fused) -- ~25us/dispatch
//     gap observed between launches.

typedef __bf16 bf16x8 __attribute__((ext_vector_type(8)));
typedef float f32x4 __attribute__((ext_vector_type(4)));
typedef unsigned int u32x4 __attribute__((ext_vector_type(4)));
using bf16_t = __hip_bfloat16;

#define B_ 4
#define T_ 256
#define U_ 64
#define DE 512
#define JD 1024
#define VV 1024

// async 16B/lane global->LDS. LDS dest is wave-uniform base + lane*16 (m104/m108).
__device__ __forceinline__ void gl2lds16(const void* g, void* l) {
  __builtin_amdgcn_global_load_lds(
      (__attribute__((address_space(1))) void*)(g),
      (__attribute__((address_space(3))) void*)(l), 16, 0, 0);
}

__device__ __forceinline__ float fast_tanh(float x) {
  float xx = fminf(fmaxf(x, -30.f), 30.f);
  float e = __expf(2.f * xx);
  return 1.f - 2.f * __builtin_amdgcn_rcpf(e + 1.f);
}

// ===================== prep: cvt enc/pred + 3 weight transposes ============
// flat grid 2688 x 256thr:
//   [0,640)    : fp32->bf16 cvt of enc (524288 elems) then pred (131072)
//   [640,1152) : W_enc  [512][1024]  -> WtE [1024][512]
//   [1152,1664): W_pred [512][1024]  -> WtP [1024][512]
//   [1664,2688): W_out  [1024][1024] -> WtO [1024][1024]
__device__ __forceinline__ void transpose_body(const float* __restrict__ src,
                                               bf16_t* __restrict__ dst,
                                               int K, int N, int bx, int by, int tid,
                                               float (*tile)[33]) {
  const int nt = bx * 32, kt = by * 32;
  const int tx = tid & 31, ty = tid >> 5;  // 32 x 8
#pragma unroll
  for (int i = 0; i < 4; ++i)
    tile[ty + i * 8][tx] = src[(size_t)(kt + ty + i * 8) * N + nt + tx];
  __syncthreads();
#pragma unroll
  for (int i = 0; i < 4; ++i)
    dst[(size_t)(nt + ty + i * 8) * K + kt + tx] = __float2bfloat16(tile[tx][ty + i * 8]);
}

__global__ __launch_bounds__(256) void prep_k(
    const float* __restrict__ enc, const float* __restrict__ pred,
    bf16_t* __restrict__ encb, bf16_t* __restrict__ predb,
    const float* __restrict__ W_enc, bf16_t* __restrict__ WtE,
    const float* __restrict__ W_pred, bf16_t* __restrict__ WtP,
    const float* __restrict__ W_out, bf16_t* __restrict__ WtO) {
  __shared__ float tile[32][33];
  const int bid = blockIdx.x, tid = threadIdx.x;
  if (bid < 640) {
    size_t i = ((size_t)bid * 256 + tid) * 4;
    const float* src;
    bf16_t* dst;
    if (i < (size_t)B_ * T_ * DE) { src = enc; dst = encb; }
    else { i -= (size_t)B_ * T_ * DE; src = pred; dst = predb; }
    f32x4 v = *(const f32x4*)(src + i);
    bf16_t o[4];
#pragma unroll
    for (int z = 0; z < 4; ++z) o[z] = __float2bfloat16(v[z]);
    *(unsigned long long*)(dst + i) = *(unsigned long long*)o;
  } else if (bid < 1152) {
    const int lb = bid - 640;
    transpose_body(W_enc, WtE, DE, JD, lb & 31, lb >> 5, tid, tile);
  } else if (bid < 1664) {
    const int lb = bid - 1152;
    transpose_body(W_pred, WtP, DE, JD, lb & 31, lb >> 5, tid, tile);
  } else {
    const int lb = bid - 1664;
    transpose_body(W_out, WtO, JD, VV, lb & 31, lb >> 5, tid, tile);
  }
}

// ============== proj2: both projections, m97-style 128x128/BK=32 ===========
__device__ __forceinline__ void proj_body(const bf16_t* __restrict__ A,
                                          const bf16_t* __restrict__ Bt,
                                          const float* __restrict__ bias,
                                          float* __restrict__ C,
                                          int m0, int n0, int N, int K) {
  __shared__ bf16_t sA[128 * 32];
  __shared__ bf16_t sB[128 * 32];
  const int tid = threadIdx.x;
  const int wave = tid >> 6, lane = tid & 63;
  const int wm = wave >> 1, wn = wave & 1;

  f32x4 acc[4][4] = {};

  for (int k0 = 0; k0 < K; k0 += 32) {
    __syncthreads();
#pragma unroll
    for (int r = 0; r < 2; ++r) {
      const int base = (wave + 4 * r) * 1024;
      const int row  = (base >> 6) + (lane >> 2);
      const int kel  = (lane & 3) * 8;
      gl2lds16(A  + (size_t)(m0 + row) * K + k0 + kel, (char*)sA + base);
      gl2lds16(Bt + (size_t)(n0 + row) * K + k0 + kel, (char*)sB + base);
    }
    __syncthreads();
    bf16x8 af[4], bfr[4];
    const int kq = (lane >> 4) * 8;
#pragma unroll
    for (int i = 0; i < 4; ++i) {
      af[i]  = *(const bf16x8*)(const void*)(sA + (wm * 64 + i * 16 + (lane & 15)) * 32 + kq);
      bfr[i] = *(const bf16x8*)(const void*)(sB + (wn * 64 + i * 16 + (lane & 15)) * 32 + kq);
    }
#pragma unroll
    for (int i = 0; i < 4; ++i)
#pragma unroll
      for (int j = 0; j < 4; ++j)
        acc[i][j] = __builtin_amdgcn_mfma_f32_16x16x32_bf16(af[i], bfr[j], acc[i][j], 0, 0, 0);
  }

  float bv[4];
#pragma unroll
  for (int j = 0; j < 4; ++j) bv[j] = bias[n0 + wn * 64 + j * 16 + (lane & 15)];
#pragma unroll
  for (int i = 0; i < 4; ++i) {
    const int row = m0 + wm * 64 + i * 16 + ((lane >> 4) << 2);
#pragma unroll
    for (int j = 0; j < 4; ++j) {
      const int col = n0 + wn * 64 + j * 16 + (lane & 15);
#pragma unroll
      for (int rr = 0; rr < 4; ++rr)
        C[(size_t)(row + rr) * N + col] = acc[i][j][rr] + bv[j];
    }
  }
}

__global__ __launch_bounds__(256) void proj2_k(
    const bf16_t* __restrict__ encb, const bf16_t* __restrict__ predb,
    const bf16_t* __restrict__ WtE, const bf16_t* __restrict__ WtP,
    const float* __restrict__ b_enc, const float* __restrict__ b_pred,
    float* __restrict__ enc_o, float* __restrict__ pred_o) {
  int bid = blockIdx.x;
  if (bid < 64) {
    // enc projection: M=1024 -> 8x8 blocks of 128
    proj_body(encb, WtE, b_enc, enc_o, (bid >> 3) * 128, (bid & 7) * 128, JD, DE);
  } else {
    bid -= 64;  // pred projection: M=256 -> 2x8 blocks
    proj_body(predb, WtP, b_pred, pred_o, (bid >> 3) * 128, (bid & 7) * 128, JD, DE);
  }
}

// ================= R5 fused vocab GEMM: 256x256, BK=32, 64KB LDS ===========
// C[M][1024] = tanh(enc_o[m>>6 rows] + pred_o)[M][1024] @ WtO^T + bias, M=65536.
// 512 thr = 8 waves (2M x 4N), per-wave 128x64. LDS: A0,A1 (16KB each, tanh'd
// bf16 written via swizzled ds_write), B0,B1 (16KB each, gl2lds + inverse-swz src).
// Swizzle (both A and B): LDS[r][c] holds global chunk c ^ ((r>>1)&3), 16B chunks.
// Pipeline: consume t; barrier; {stage B(t+2) (2 gl_lds), tanh+write A(t+2) from
// regs loaded a full tile earlier}; vmcnt(2)+lgkm(0); barrier. vmcnt never 0
// in steady state (B(t+2)'s 2 loads stay in flight).

__device__ __forceinline__ void stage_btile(const bf16_t* __restrict__ Bt,
                                            int n0, int k0, char* bb, int wave, int lane) {
  const int rw = lane >> 2;   // row within 16-row wave slice
  const int cl = lane & 3;    // linear LDS chunk this lane fills
#pragma unroll
  for (int g = 0; g < 2; ++g) {
    const int r  = g * 128 + wave * 16 + rw;
    const int cg = cl ^ ((r >> 1) & 3);  // inverse-swizzled global chunk
    gl2lds16(Bt + (size_t)(n0 + r) * JD + k0 + cg * 8, bb + (g * 128 + wave * 16) * 64);
  }
}

__device__ __forceinline__ void load_ep(const float* __restrict__ enc_o,
                                        const float* __restrict__ pred_o,
                                        int m0, int r, int h, int k0,
                                        f32x4 e[4], f32x4 p[4]) {
  const int m = m0 + r;
  const int enc_row  = m >> 6;
  const int pred_row = ((m >> 14) << 6) | (m & 63);
  const float* pe = enc_o  + (size_t)enc_row  * JD + k0 + h * 16;
  const float* pp = pred_o + (size_t)pred_row * JD + k0 + h * 16;
#pragma unroll
  for (int q = 0; q < 4; ++q) {
    e[q] = *(const f32x4*)(pe + q * 4);
    p[q] = *(const f32x4*)(pp + q * 4);
  }
}

__device__ __forceinline__ void tanh_write_A(const f32x4 e[4], const f32x4 p[4],
                                             char* ab, int r, int h) {
  bf16_t vals[16];
#pragma unroll
  for (int q = 0; q < 4; ++q)
#pragma unroll
    for (int z = 0; z < 4; ++z)
      vals[q * 4 + z] = __float2bfloat16(fast_tanh(e[q][z] + p[q][z]));
  const int key = (r >> 1) & 3;
  *(u32x4*)(void*)(ab + r * 64 + ((2 * h)     ^ key) * 16) = ((const u32x4*)(const void*)vals)[0];
  *(u32x4*)(void*)(ab + r * 64 + ((2 * h + 1) ^ key) * 16) = ((const u32x4*)(const void*)vals)[1];
}

__global__ __launch_bounds__(512, 2) void vocab_fused_k(
    const float* __restrict__ enc_o,   // [B*T][JD] f32
    const float* __restrict__ pred_o,  // [B*U][JD] f32
    const bf16_t* __restrict__ Bt,     // [VV][JD] W_out^T bf16
    const float* __restrict__ bias,    // [VV]
    float* __restrict__ C) {           // [M][VV]
  __shared__ char smem[65536];  // A0 @0, A1 @16384, B0 @32768, B1 @49152
  const int tid  = threadIdx.x;
  const int wave = tid >> 6, lane = tid & 63;
  const int wm = wave >> 2, wn = wave & 3;

  // T1: bijective XCD swizzle (grid = 1024, divisible by 8), n-fastest order.
  const int cpx = gridDim.x >> 3;
  const int b   = blockIdx.x;
  const int lb  = (b & 7) * cpx + (b >> 3);
  const int n0  = (lb & 3) * 256;
  const int m0  = (lb >> 2) * 256;

  const int ar = tid >> 1;   // A-stage: row this thread generates
  const int ah = tid & 1;    // A-stage: k-half (16 elems)

  f32x4 acc[8][4] = {};
  const int NT = JD / 32;  // 32 K-tiles

  // ---- prologue: A0,A1 computed+written; B0,B1 staged ----
  {
    f32x4 e[4], p[4];
    load_ep(enc_o, pred_o, m0, ar, ah, 0, e, p);
    tanh_write_A(e, p, smem, ar, ah);
    load_ep(enc_o, pred_o, m0, ar, ah, 32, e, p);
    tanh_write_A(e, p, smem + 16384, ar, ah);
  }
  stage_btile(Bt, n0, 0,  smem + 32768, wave, lane);
  stage_btile(Bt, n0, 32, smem + 49152, wave, lane);
  asm volatile("s_waitcnt vmcnt(2) lgkmcnt(0)" ::: "memory");  // B0 landed; B1 flying
  __builtin_amdgcn_s_barrier();
  __builtin_amdgcn_sched_barrier(0);

  // enc/pred for K-tile 2, issued a full tile ahead of use
  f32x4 e2[4], p2[4];
  load_ep(enc_o, pred_o, m0, ar, ah, 2 * 32, e2, p2);
  __builtin_amdgcn_sched_barrier(0);

  for (int t = 0; t < NT; ++t) {
    const char* ab = smem + (t & 1) * 16384;
    const char* bb = smem + 32768 + (t & 1) * 16384;
    const int kq = lane >> 4;  // k-chunk 0..3 before swizzle

    // ---- consume tile t: 32 MFMA in two 16-MFMA clusters ----
    bf16x8 bfr[4];
#pragma unroll
    for (int j = 0; j < 4; ++j) {
      const int rb = wn * 64 + j * 16 + (lane & 15);
      const int cb = kq ^ ((rb >> 1) & 3);
      bfr[j] = *(const bf16x8*)(const void*)(bb + rb * 64 + cb * 16);
    }
#pragma unroll
    for (int mh = 0; mh < 2; ++mh) {
      bf16x8 af[4];
#pragma unroll
      for (int i = 0; i < 4; ++i) {
        const int ra = wm * 128 + mh * 64 + i * 16 + (lane & 15);
        const int ca = kq ^ ((ra >> 1) & 3);
        af[i] = *(const bf16x8*)(const void*)(ab + ra * 64 + ca * 16);
      }
      __builtin_amdgcn_s_setprio(1);
#pragma unroll
      for (int i = 0; i < 4; ++i)
#pragma unroll
        for (int j = 0; j < 4; ++j)
          acc[mh * 4 + i][j] =
              __builtin_amdgcn_mfma_f32_16x16x32_bf16(af[i], bfr[j], acc[mh * 4 + i][j], 0, 0, 0);
      __builtin_amdgcn_s_setprio(0);
    }

    // ---- boundary: restage consumed buffers, counted wait ----
    if (t + 1 < NT) {
      __builtin_amdgcn_sched_barrier(0);
      __builtin_amdgcn_s_barrier();  // all waves done reading buf[t&1]
      if (t + 2 < NT) {
        stage_btile(Bt, n0, (t + 2) * 32, (char*)smem + 32768 + (t & 1) * 16384, wave, lane);
        // tanh inputs were loaded a full tile ago; compiler's wait ~vmcnt(2)
        tanh_write_A(e2, p2, (char*)smem + (t & 1) * 16384, ar, ah);
        asm volatile("s_waitcnt vmcnt(2) lgkmcnt(0)" ::: "memory");  // B(t+1) landed; A-writes visible
      } else {
        asm volatile("s_waitcnt vmcnt(0) lgkmcnt(0)" ::: "memory");  // tail drain (once)
      }
      __builtin_amdgcn_s_barrier();  // tile t+1 fully visible
      __builtin_amdgcn_sched_barrier(0);
      if (t + 3 < NT) {
        load_ep(enc_o, pred_o, m0, ar, ah, (t + 3) * 32, e2, p2);
        __builtin_amdgcn_sched_barrier(0);
      }
    }
  }

  // ---- epilogue (bias here so the K-loop has no stray VMEM) ----
  float bv[4];
#pragma unroll
  for (int j = 0; j < 4; ++j) bv[j] = bias[n0 + wn * 64 + j * 16 + (lane & 15)];
#pragma unroll
  for (int i = 0; i < 8; ++i) {
    const int row = m0 + wm * 128 + i * 16 + ((lane >> 4) << 2);
#pragma unroll
    for (int j = 0; j < 4; ++j) {
      const int col = n0 + wn * 64 + j * 16 + (lane & 15);
#pragma unroll
      for (int rr = 0; rr < 4; ++rr)
        C[(size_t)(row + rr) * VV + col] = acc[i][j][rr] + bv[j];
    }
  }
}

extern "C" void kernel_launch(void* const* d_in, const int* in_sizes, int n_in,
                              void* d_out, int out_size, void* d_ws, size_t ws_size,
                              hipStream_t stream) {
  const float* enc    = (const float*)d_in[0];  // [4,256,512]
  const float* pred   = (const float*)d_in[1];  // [4,64,512]
  const float* W_enc  = (const float*)d_in[2];  // [512,1024]
  const float* b_enc  = (const float*)d_in[3];  // [1024]
  const float* W_pred = (const float*)d_in[4];  // [512,1024]
  const float* b_pred = (const float*)d_in[5];  // [1024]
  const float* W_out  = (const float*)d_in[6];  // [1024,1024]
  const float* b_out  = (const float*)d_in[7];  // [1024]
  float* out = (float*)d_out;                   // [4,256,64,1024]

  char* ws = (char*)d_ws;
  bf16_t* encb   = (bf16_t*)(ws + 0x000000);  // 1 MB   [1024][512]
  bf16_t* predb  = (bf16_t*)(ws + 0x100000);  // 256 KB [256][512]
  bf16_t* WtE    = (bf16_t*)(ws + 0x140000);  // 1 MB   [1024][512]
  bf16_t* WtP    = (bf16_t*)(ws + 0x240000);  // 1 MB   [1024][512]
  bf16_t* WtO    = (bf16_t*)(ws + 0x340000);  // 2 MB   [1024][1024]
  float*  enc_o  = (float*) (ws + 0x540000);  // 4 MB   [1024][1024]
  float*  pred_o = (float*) (ws + 0x940000);  // 1 MB   [256][1024]

  // 1) prep: cvt enc/pred to bf16 + transpose all three weights (one dispatch)
  prep_k<<<2688, 256, 0, stream>>>(enc, pred, encb, predb, W_enc, WtE, W_pred, WtP, W_out, WtO);

  // 2) both projections (bias folded; joint adds them via enc_o + pred_o)
  proj2_k<<<80, 256, 0, stream>>>(encb, predb, WtE, WtP, b_enc, b_pred, enc_o, pred_o);

  // 3) fused tanh + vocab GEMM (A-tiles generated in-kernel; no joint buffer)
  vocab_fused_k<<<dim3(((B_*T_*U_) / 256) * (VV / 256)), 512, 0, stream>>>(
      enc_o, pred_o, WtO, b_out, out);
}

// Round 4
// 462.821 us; speedup vs baseline: 1.0732x; 1.0732x over previous
//
#include <hip/hip_runtime.h>
#include <hip/hip_bf16.h>

// Transducer joint: logits[b,t,u,:] = tanh(enc_out[b,t,:] + pred_out[b,u,:]) @ W_out + b_out
// B=4 T=256 U=64 D=512 J=1024 V=1024.
// R4: vocab 256x256/BK=32 gl2lds double-buffer: 184us, MfmaUtil 31% -> latency-bound
//     (loads have only ~1 consume phase in flight vs ~900cyc HBM latency).
// R5: tanh-fusion REGRESSED (264us): tanh VALU serialized between barriers. Reverted.
// R6: reg-staged prefetch depth 2: issue tile t+2's global loads into REGISTERS at
//     consume(t) start (~2 tiles ~800cyc in flight), ds_write at the boundary into
//     the non-consumed buffer -> ONE barrier/tile, compiler-exact vmcnt(4) before
//     ds_write. Swizzle applied directly on ds_write (bank-uniform, verified by calc).
//     T1 XCD swizzle + T2 chunk-XOR + T5 setprio kept. 4 dispatches total.

typedef __bf16 bf16x8 __attribute__((ext_vector_type(8)));
typedef float f32x4 __attribute__((ext_vector_type(4)));
typedef unsigned int u32x4 __attribute__((ext_vector_type(4)));
using bf16_t = __hip_bfloat16;

#define B_ 4
#define T_ 256
#define U_ 64
#define DE 512
#define JD 1024
#define VV 1024

// async 16B/lane global->LDS (used by proj GEMM only).
__device__ __forceinline__ void gl2lds16(const void* g, void* l) {
  __builtin_amdgcn_global_load_lds(
      (__attribute__((address_space(1))) void*)(g),
      (__attribute__((address_space(3))) void*)(l), 16, 0, 0);
}

__device__ __forceinline__ float fast_tanh(float x) {
  float xx = fminf(fmaxf(x, -30.f), 30.f);
  float e = __expf(2.f * xx);
  return 1.f - 2.f * __builtin_amdgcn_rcpf(e + 1.f);
}

// ===================== prep: cvt enc/pred + 3 weight transposes ============
__device__ __forceinline__ void transpose_body(const float* __restrict__ src,
                                               bf16_t* __restrict__ dst,
                                               int K, int N, int bx, int by, int tid,
                                               float (*tile)[33]) {
  const int nt = bx * 32, kt = by * 32;
  const int tx = tid & 31, ty = tid >> 5;  // 32 x 8
#pragma unroll
  for (int i = 0; i < 4; ++i)
    tile[ty + i * 8][tx] = src[(size_t)(kt + ty + i * 8) * N + nt + tx];
  __syncthreads();
#pragma unroll
  for (int i = 0; i < 4; ++i)
    dst[(size_t)(nt + ty + i * 8) * K + kt + tx] = __float2bfloat16(tile[tx][ty + i * 8]);
}

__global__ __launch_bounds__(256) void prep_k(
    const float* __restrict__ enc, const float* __restrict__ pred,
    bf16_t* __restrict__ encb, bf16_t* __restrict__ predb,
    const float* __restrict__ W_enc, bf16_t* __restrict__ WtE,
    const float* __restrict__ W_pred, bf16_t* __restrict__ WtP,
    const float* __restrict__ W_out, bf16_t* __restrict__ WtO) {
  __shared__ float tile[32][33];
  const int bid = blockIdx.x, tid = threadIdx.x;
  if (bid < 640) {
    size_t i = ((size_t)bid * 256 + tid) * 4;
    const float* src;
    bf16_t* dst;
    if (i < (size_t)B_ * T_ * DE) { src = enc; dst = encb; }
    else { i -= (size_t)B_ * T_ * DE; src = pred; dst = predb; }
    f32x4 v = *(const f32x4*)(src + i);
    bf16_t o[4];
#pragma unroll
    for (int z = 0; z < 4; ++z) o[z] = __float2bfloat16(v[z]);
    *(unsigned long long*)(dst + i) = *(unsigned long long*)o;
  } else if (bid < 1152) {
    const int lb = bid - 640;
    transpose_body(W_enc, WtE, DE, JD, lb & 31, lb >> 5, tid, tile);
  } else if (bid < 1664) {
    const int lb = bid - 1152;
    transpose_body(W_pred, WtP, DE, JD, lb & 31, lb >> 5, tid, tile);
  } else {
    const int lb = bid - 1664;
    transpose_body(W_out, WtO, JD, VV, lb & 31, lb >> 5, tid, tile);
  }
}

// ============== proj2: both projections, m97-style 128x128/BK=32 ===========
__device__ __forceinline__ void proj_body(const bf16_t* __restrict__ A,
                                          const bf16_t* __restrict__ Bt,
                                          const float* __restrict__ bias,
                                          float* __restrict__ C,
                                          int m0, int n0, int N, int K) {
  __shared__ bf16_t sA[128 * 32];
  __shared__ bf16_t sB[128 * 32];
  const int tid = threadIdx.x;
  const int wave = tid >> 6, lane = tid & 63;
  const int wm = wave >> 1, wn = wave & 1;

  f32x4 acc[4][4] = {};

  for (int k0 = 0; k0 < K; k0 += 32) {
    __syncthreads();
#pragma unroll
    for (int r = 0; r < 2; ++r) {
      const int base = (wave + 4 * r) * 1024;
      const int row  = (base >> 6) + (lane >> 2);
      const int kel  = (lane & 3) * 8;
      gl2lds16(A  + (size_t)(m0 + row) * K + k0 + kel, (char*)sA + base);
      gl2lds16(Bt + (size_t)(n0 + row) * K + k0 + kel, (char*)sB + base);
    }
    __syncthreads();
    bf16x8 af[4], bfr[4];
    const int kq = (lane >> 4) * 8;
#pragma unroll
    for (int i = 0; i < 4; ++i) {
      af[i]  = *(const bf16x8*)(const void*)(sA + (wm * 64 + i * 16 + (lane & 15)) * 32 + kq);
      bfr[i] = *(const bf16x8*)(const void*)(sB + (wn * 64 + i * 16 + (lane & 15)) * 32 + kq);
    }
#pragma unroll
    for (int i = 0; i < 4; ++i)
#pragma unroll
      for (int j = 0; j < 4; ++j)
        acc[i][j] = __builtin_amdgcn_mfma_f32_16x16x32_bf16(af[i], bfr[j], acc[i][j], 0, 0, 0);
  }

  float bv[4];
#pragma unroll
  for (int j = 0; j < 4; ++j) bv[j] = bias[n0 + wn * 64 + j * 16 + (lane & 15)];
#pragma unroll
  for (int i = 0; i < 4; ++i) {
    const int row = m0 + wm * 64 + i * 16 + ((lane >> 4) << 2);
#pragma unroll
    for (int j = 0; j < 4; ++j) {
      const int col = n0 + wn * 64 + j * 16 + (lane & 15);
#pragma unroll
      for (int rr = 0; rr < 4; ++rr)
        C[(size_t)(row + rr) * N + col] = acc[i][j][rr] + bv[j];
    }
  }
}

__global__ __launch_bounds__(256) void proj2_k(
    const bf16_t* __restrict__ encb, const bf16_t* __restrict__ predb,
    const bf16_t* __restrict__ WtE, const bf16_t* __restrict__ WtP,
    const float* __restrict__ b_enc, const float* __restrict__ b_pred,
    float* __restrict__ enc_o, float* __restrict__ pred_o) {
  int bid = blockIdx.x;
  if (bid < 64) {
    proj_body(encb, WtE, b_enc, enc_o, (bid >> 3) * 128, (bid & 7) * 128, JD, DE);
  } else {
    bid -= 64;
    proj_body(predb, WtP, b_pred, pred_o, (bid >> 3) * 128, (bid & 7) * 128, JD, DE);
  }
}

// ------------- tanh materialize: joint[m][j] = tanh(enc_o + pred_o), bf16 ---
__global__ __launch_bounds__(256) void tanh_mat_k(
    const float* __restrict__ enc_o,   // [B*T][JD]
    const float* __restrict__ pred_o,  // [B*U][JD]
    bf16_t* __restrict__ joint) {      // [B*T*U][JD]
  size_t i = ((size_t)blockIdx.x * 256 + threadIdx.x) * 8;
  const int m = (int)(i >> 10);
  const int j = (int)(i & 1023);
  const int enc_row  = m >> 6;
  const int pred_row = ((m >> 14) << 6) | (m & 63);
  const f32x4* pe = (const f32x4*)(enc_o  + (size_t)enc_row  * JD + j);
  const f32x4* pp = (const f32x4*)(pred_o + (size_t)pred_row * JD + j);
  bf16_t vals[8];
#pragma unroll
  for (int q = 0; q < 2; ++q) {
    f32x4 e = pe[q], p = pp[q];
#pragma unroll
    for (int z = 0; z < 4; ++z)
      vals[q * 4 + z] = __float2bfloat16(fast_tanh(e[z] + p[z]));
  }
  *(u32x4*)(void*)(joint + i) = *(const u32x4*)(const void*)vals;
}

// ============ R6 vocab GEMM: 256x256/BK=32, reg-staged depth-2 =============
// C[M][1024] = A[M][1024] * Bt[1024][1024]^T + bias, M=65536.
// 512 thr = 8 waves (2M x 4N), per-wave 128x64.
// LDS 64KB static: bufA0@0, bufB0@16K, bufA1@32K, bufB1@48K (each 256 rows x 64B).
// Per thread per tile: row ra=tid>>1, chunk pair c0=(tid&1)*2; 4 global_load_dwordx4
// into regs (2 A + 2 B). Swizzle LDS[r][c] = global chunk c ^ ((r>>1)&3), applied
// on the ds_write (bank-uniform across the wave).
// Schedule per tile t: [issue loads(t+2) -> regs] [consume t: ds_read+32 MFMA]
// [ds_write set(t+1) -> other buffer (compiler-auto vmcnt(4))] [lgkmcnt(0)]
// [s_barrier]. Loads are ~2 consume phases (~800cyc) in flight -> HBM latency
// covered; ONE barrier per tile.

struct RS { u32x4 v[4]; };  // a0,a1,b0,b1 — static indices only (rule #20)

__global__ __launch_bounds__(512, 2) void vocab_gemm9_k(
    const bf16_t* __restrict__ A,   // [M][JD] joint bf16
    const bf16_t* __restrict__ Bt,  // [VV][JD] W_out^T bf16
    const float* __restrict__ bias, // [VV]
    float* __restrict__ C) {        // [M][VV]
  __shared__ char smem[65536];
  const int tid  = threadIdx.x;
  const int wave = tid >> 6, lane = tid & 63;
  const int wm = wave >> 2, wn = wave & 3;

  // T1: bijective XCD swizzle (grid = 1024, divisible by 8), n-fastest order.
  const int cpx = gridDim.x >> 3;
  const int b   = blockIdx.x;
  const int lb  = (b & 7) * cpx + (b >> 3);
  const int n0  = (lb & 3) * 256;
  const int m0  = (lb >> 2) * 256;

  // staging geometry
  const int ra  = tid >> 1;         // 0..255
  const int c0  = (tid & 1) * 2;    // chunk pair {c0, c0+1}
  const int key = (ra >> 1) & 3;    // T2 swizzle key
  const bf16_t* pa = A  + (size_t)(m0 + ra) * JD;
  const bf16_t* pb = Bt + (size_t)(n0 + ra) * JD;
  const int go0 = c0 * 8, go1 = (c0 + 1) * 8;           // global elem offsets
  const int lo0 = ((c0 ^ key)) * 16, lo1 = ((c0 + 1) ^ key) * 16;  // swz LDS byte offs

  char* abuf[2] = { smem, smem + 32768 };

  f32x4 acc[8][4] = {};
  const int NT = JD / 32;  // 32

#define ISSUE(S, K0)                                           \
  do {                                                         \
    (S).v[0] = *(const u32x4*)(const void*)(pa + (K0) + go0);  \
    (S).v[1] = *(const u32x4*)(const void*)(pa + (K0) + go1);  \
    (S).v[2] = *(const u32x4*)(const void*)(pb + (K0) + go0);  \
    (S).v[3] = *(const u32x4*)(const void*)(pb + (K0) + go1);  \
  } while (0)

#define WRITE(S, AB)                                           \
  do {                                                         \
    char* ab_ = (AB);                                          \
    *(u32x4*)(void*)(ab_ + ra * 64 + lo0)         = (S).v[0];  \
    *(u32x4*)(void*)(ab_ + ra * 64 + lo1)         = (S).v[1];  \
    *(u32x4*)(void*)(ab_ + 16384 + ra * 64 + lo0) = (S).v[2];  \
    *(u32x4*)(void*)(ab_ + 16384 + ra * 64 + lo1) = (S).v[3];  \
  } while (0)

#define BOUND()                                                \
  do {                                                         \
    asm volatile("s_waitcnt lgkmcnt(0)" ::: "memory");         \
    __builtin_amdgcn_s_barrier();                              \
    __builtin_amdgcn_sched_barrier(0);                         \
  } while (0)

#define CONSUME(AB)                                                            \
  do {                                                                         \
    const char* ab_ = (AB);                                                    \
    const char* bb_ = ab_ + 16384;                                             \
    const int kq = lane >> 4;                                                  \
    bf16x8 bfr[4];                                                             \
    _Pragma("unroll")                                                          \
    for (int j = 0; j < 4; ++j) {                                              \
      const int rb = wn * 64 + j * 16 + (lane & 15);                           \
      const int cb = kq ^ ((rb >> 1) & 3);                                     \
      bfr[j] = *(const bf16x8*)(const void*)(bb_ + rb * 64 + cb * 16);         \
    }                                                                          \
    _Pragma("unroll")                                                          \
    for (int mh = 0; mh < 2; ++mh) {                                           \
      bf16x8 af[4];                                                            \
      _Pragma("unroll")                                                        \
      for (int i = 0; i < 4; ++i) {                                            \
        const int rr_ = wm * 128 + mh * 64 + i * 16 + (lane & 15);             \
        const int ca = kq ^ ((rr_ >> 1) & 3);                                  \
        af[i] = *(const bf16x8*)(const void*)(ab_ + rr_ * 64 + ca * 16);       \
      }                                                                        \
      __builtin_amdgcn_s_setprio(1);                                           \
      _Pragma("unroll")                                                        \
      for (int i = 0; i < 4; ++i)                                              \
        _Pragma("unroll")                                                      \
        for (int j = 0; j < 4; ++j)                                            \
          acc[mh * 4 + i][j] = __builtin_amdgcn_mfma_f32_16x16x32_bf16(        \
              af[i], bfr[j], acc[mh * 4 + i][j], 0, 0, 0);                     \
      __builtin_amdgcn_s_setprio(0);                                           \
    }                                                                          \
  } while (0)

  RS rsE, rsO;
  // prologue: tiles 0,1 into regs; write tile 0; barrier.
  ISSUE(rsE, 0);
  ISSUE(rsO, 32);
  WRITE(rsE, abuf[0]);  // compiler emits vmcnt(4): waits tile0, tile1 stays in flight
  BOUND();

  for (int t = 0; t < NT; t += 2) {
    // ---- even tile t ----
    if (t + 2 < NT) ISSUE(rsE, (t + 2) * 32);   // rsE was written to LDS at B_{t-1}
    CONSUME(abuf[0]);
    WRITE(rsO, abuf[1]);                         // tile t+1 (auto vmcnt(4))
    BOUND();
    // ---- odd tile t+1 ----
    if (t + 3 < NT) ISSUE(rsO, (t + 3) * 32);
    CONSUME(abuf[1]);
    if (t + 2 < NT) {
      WRITE(rsE, abuf[0]);                       // tile t+2
      BOUND();
    }
  }

#undef ISSUE
#undef WRITE
#undef BOUND
#undef CONSUME

  // ---- epilogue ----
  float bv[4];
#pragma unroll
  for (int j = 0; j < 4; ++j) bv[j] = bias[n0 + wn * 64 + j * 16 + (lane & 15)];
#pragma unroll
  for (int i = 0; i < 8; ++i) {
    const int row = m0 + wm * 128 + i * 16 + ((lane >> 4) << 2);
#pragma unroll
    for (int j = 0; j < 4; ++j) {
      const int col = n0 + wn * 64 + j * 16 + (lane & 15);
#pragma unroll
      for (int rr = 0; rr < 4; ++rr)
        C[(size_t)(row + rr) * VV + col] = acc[i][j][rr] + bv[j];
    }
  }
}

extern "C" void kernel_launch(void* const* d_in, const int* in_sizes, int n_in,
                              void* d_out, int out_size, void* d_ws, size_t ws_size,
                              hipStream_t stream) {
  const float* enc    = (const float*)d_in[0];  // [4,256,512]
  const float* pred   = (const float*)d_in[1];  // [4,64,512]
  const float* W_enc  = (const float*)d_in[2];  // [512,1024]
  const float* b_enc  = (const float*)d_in[3];  // [1024]
  const float* W_pred = (const float*)d_in[4];  // [512,1024]
  const float* b_pred = (const float*)d_in[5];  // [1024]
  const float* W_out  = (const float*)d_in[6];  // [1024,1024]
  const float* b_out  = (const float*)d_in[7];  // [1024]
  float* out = (float*)d_out;                   // [4,256,64,1024]

  char* ws = (char*)d_ws;
  bf16_t* encb   = (bf16_t*)(ws + 0x000000);  // 1 MB   [1024][512]
  bf16_t* predb  = (bf16_t*)(ws + 0x100000);  // 256 KB [256][512]
  bf16_t* WtE    = (bf16_t*)(ws + 0x140000);  // 1 MB   [1024][512]
  bf16_t* WtP    = (bf16_t*)(ws + 0x240000);  // 1 MB   [1024][512]
  bf16_t* WtO    = (bf16_t*)(ws + 0x340000);  // 2 MB   [1024][1024]
  float*  enc_o  = (float*) (ws + 0x540000);  // 4 MB   [1024][1024]
  float*  pred_o = (float*) (ws + 0x940000);  // 1 MB   [256][1024]
  bf16_t* joint  = (bf16_t*)(ws + 0xA40000);  // 128 MB [65536][1024]

  // 1) prep: cvt enc/pred + transpose all three weights
  prep_k<<<2688, 256, 0, stream>>>(enc, pred, encb, predb, W_enc, WtE, W_pred, WtP, W_out, WtO);
  // 2) both projections (bias folded)
  proj2_k<<<80, 256, 0, stream>>>(encb, predb, WtE, WtP, b_enc, b_pred, enc_o, pred_o);
  // 3) tanh materialize (bf16 joint)
  tanh_mat_k<<<(B_*T_*U_) * JD / (8 * 256), 256, 0, stream>>>(enc_o, pred_o, joint);
  // 4) deep-pipelined vocab GEMM
  vocab_gemm9_k<<<dim3(((B_*T_*U_) / 256) * (VV / 256)), 512, 0, stream>>>(
      joint, WtO, b_out, out);
}

// Round 5
// 435.863 us; speedup vs baseline: 1.1396x; 1.0619x over previous
//
#include <hip/hip_runtime.h>
#include <hip/hip_bf16.h>

// Transducer joint: logits[b,t,u,:] = tanh(enc_out[b,t,:] + pred_out[b,u,:]) @ W_out + b_out
// B=4 T=256 U=64 D=512 J=1024 V=1024.
// R4: 256x256/BK=32 gl2lds 2-phase: 184us, MfmaUtil 31%.
// R5: tanh-fusion REGRESSED (264us, tanh serialized between barriers). Reverted.
// R6: reg-staged depth-2, still coarse 2-phase: 193us, MfmaUtil 30%. Conclusion:
//     staging mechanism irrelevant; schedule granularity is the bottleneck.
// R7: m201-style fine-phase schedule @ 64KB static LDS: 4 phases/K-step, each
//     {ds_read subtile || stage half-tile -> barrier -> lgkmcnt(0) -> 8 MFMA
//     (one C-quadrant) -> barrier}. Counted vmcnt(2) once per K-step, never 0.
//     Stagings: B-halves(s+1) at P0/P1 (other dbuf), A-halves(s+2) at P3 (own
//     dbuf, A-reads end at P2) -> every half-tile >=2.5 phases in flight.
//     T1 XCD swizzle + T2 (r>>1)&3 chunk-XOR + T5 setprio kept. Fragment /
//     acc / epilogue layout identical to verified R4/R6.

typedef __bf16 bf16x8 __attribute__((ext_vector_type(8)));
typedef float f32x4 __attribute__((ext_vector_type(4)));
typedef unsigned int u32x4 __attribute__((ext_vector_type(4)));
using bf16_t = __hip_bfloat16;

#define B_ 4
#define T_ 256
#define U_ 64
#define DE 512
#define JD 1024
#define VV 1024

// async 16B/lane global->LDS. LDS dest is wave-uniform base + lane*16 (m104/m108).
__device__ __forceinline__ void gl2lds16(const void* g, void* l) {
  __builtin_amdgcn_global_load_lds(
      (__attribute__((address_space(1))) void*)(g),
      (__attribute__((address_space(3))) void*)(l), 16, 0, 0);
}

__device__ __forceinline__ float fast_tanh(float x) {
  float xx = fminf(fmaxf(x, -30.f), 30.f);
  float e = __expf(2.f * xx);
  return 1.f - 2.f * __builtin_amdgcn_rcpf(e + 1.f);
}

// ===================== prep: cvt enc/pred + 3 weight transposes ============
__device__ __forceinline__ void transpose_body(const float* __restrict__ src,
                                               bf16_t* __restrict__ dst,
                                               int K, int N, int bx, int by, int tid,
                                               float (*tile)[33]) {
  const int nt = bx * 32, kt = by * 32;
  const int tx = tid & 31, ty = tid >> 5;  // 32 x 8
#pragma unroll
  for (int i = 0; i < 4; ++i)
    tile[ty + i * 8][tx] = src[(size_t)(kt + ty + i * 8) * N + nt + tx];
  __syncthreads();
#pragma unroll
  for (int i = 0; i < 4; ++i)
    dst[(size_t)(nt + ty + i * 8) * K + kt + tx] = __float2bfloat16(tile[tx][ty + i * 8]);
}

__global__ __launch_bounds__(256) void prep_k(
    const float* __restrict__ enc, const float* __restrict__ pred,
    bf16_t* __restrict__ encb, bf16_t* __restrict__ predb,
    const float* __restrict__ W_enc, bf16_t* __restrict__ WtE,
    const float* __restrict__ W_pred, bf16_t* __restrict__ WtP,
    const float* __restrict__ W_out, bf16_t* __restrict__ WtO) {
  __shared__ float tile[32][33];
  const int bid = blockIdx.x, tid = threadIdx.x;
  if (bid < 640) {
    size_t i = ((size_t)bid * 256 + tid) * 4;
    const float* src;
    bf16_t* dst;
    if (i < (size_t)B_ * T_ * DE) { src = enc; dst = encb; }
    else { i -= (size_t)B_ * T_ * DE; src = pred; dst = predb; }
    f32x4 v = *(const f32x4*)(src + i);
    bf16_t o[4];
#pragma unroll
    for (int z = 0; z < 4; ++z) o[z] = __float2bfloat16(v[z]);
    *(unsigned long long*)(dst + i) = *(unsigned long long*)o;
  } else if (bid < 1152) {
    const int lb = bid - 640;
    transpose_body(W_enc, WtE, DE, JD, lb & 31, lb >> 5, tid, tile);
  } else if (bid < 1664) {
    const int lb = bid - 1152;
    transpose_body(W_pred, WtP, DE, JD, lb & 31, lb >> 5, tid, tile);
  } else {
    const int lb = bid - 1664;
    transpose_body(W_out, WtO, JD, VV, lb & 31, lb >> 5, tid, tile);
  }
}

// ============== proj2: both projections, m97-style 128x128/BK=32 ===========
__device__ __forceinline__ void proj_body(const bf16_t* __restrict__ A,
                                          const bf16_t* __restrict__ Bt,
                                          const float* __restrict__ bias,
                                          float* __restrict__ C,
                                          int m0, int n0, int N, int K) {
  __shared__ bf16_t sA[128 * 32];
  __shared__ bf16_t sB[128 * 32];
  const int tid = threadIdx.x;
  const int wave = tid >> 6, lane = tid & 63;
  const int wm = wave >> 1, wn = wave & 1;

  f32x4 acc[4][4] = {};

  for (int k0 = 0; k0 < K; k0 += 32) {
    __syncthreads();
#pragma unroll
    for (int r = 0; r < 2; ++r) {
      const int base = (wave + 4 * r) * 1024;
      const int row  = (base >> 6) + (lane >> 2);
      const int kel  = (lane & 3) * 8;
      gl2lds16(A  + (size_t)(m0 + row) * K + k0 + kel, (char*)sA + base);
      gl2lds16(Bt + (size_t)(n0 + row) * K + k0 + kel, (char*)sB + base);
    }
    __syncthreads();
    bf16x8 af[4], bfr[4];
    const int kq = (lane >> 4) * 8;
#pragma unroll
    for (int i = 0; i < 4; ++i) {
      af[i]  = *(const bf16x8*)(const void*)(sA + (wm * 64 + i * 16 + (lane & 15)) * 32 + kq);
      bfr[i] = *(const bf16x8*)(const void*)(sB + (wn * 64 + i * 16 + (lane & 15)) * 32 + kq);
    }
#pragma unroll
    for (int i = 0; i < 4; ++i)
#pragma unroll
      for (int j = 0; j < 4; ++j)
        acc[i][j] = __builtin_amdgcn_mfma_f32_16x16x32_bf16(af[i], bfr[j], acc[i][j], 0, 0, 0);
  }

  float bv[4];
#pragma unroll
  for (int j = 0; j < 4; ++j) bv[j] = bias[n0 + wn * 64 + j * 16 + (lane & 15)];
#pragma unroll
  for (int i = 0; i < 4; ++i) {
    const int row = m0 + wm * 64 + i * 16 + ((lane >> 4) << 2);
#pragma unroll
    for (int j = 0; j < 4; ++j) {
      const int col = n0 + wn * 64 + j * 16 + (lane & 15);
#pragma unroll
      for (int rr = 0; rr < 4; ++rr)
        C[(size_t)(row + rr) * N + col] = acc[i][j][rr] + bv[j];
    }
  }
}

__global__ __launch_bounds__(256) void proj2_k(
    const bf16_t* __restrict__ encb, const bf16_t* __restrict__ predb,
    const bf16_t* __restrict__ WtE, const bf16_t* __restrict__ WtP,
    const float* __restrict__ b_enc, const float* __restrict__ b_pred,
    float* __restrict__ enc_o, float* __restrict__ pred_o) {
  int bid = blockIdx.x;
  if (bid < 64) {
    proj_body(encb, WtE, b_enc, enc_o, (bid >> 3) * 128, (bid & 7) * 128, JD, DE);
  } else {
    bid -= 64;
    proj_body(predb, WtP, b_pred, pred_o, (bid >> 3) * 128, (bid & 7) * 128, JD, DE);
  }
}

// ------------- tanh materialize: joint[m][j] = tanh(enc_o + pred_o), bf16 ---
__global__ __launch_bounds__(256) void tanh_mat_k(
    const float* __restrict__ enc_o,   // [B*T][JD]
    const float* __restrict__ pred_o,  // [B*U][JD]
    bf16_t* __restrict__ joint) {      // [B*T*U][JD]
  size_t i = ((size_t)blockIdx.x * 256 + threadIdx.x) * 8;
  const int m = (int)(i >> 10);
  const int j = (int)(i & 1023);
  const int enc_row  = m >> 6;
  const int pred_row = ((m >> 14) << 6) | (m & 63);
  const f32x4* pe = (const f32x4*)(enc_o  + (size_t)enc_row  * JD + j);
  const f32x4* pp = (const f32x4*)(pred_o + (size_t)pred_row * JD + j);
  bf16_t vals[8];
#pragma unroll
  for (int q = 0; q < 2; ++q) {
    f32x4 e = pe[q], p = pp[q];
#pragma unroll
    for (int z = 0; z < 4; ++z)
      vals[q * 4 + z] = __float2bfloat16(fast_tanh(e[z] + p[z]));
  }
  *(u32x4*)(void*)(joint + i) = *(const u32x4*)(const void*)vals;
}

// ====== R7 vocab GEMM: 256x256/BK=32, 4-phase fine-interleave schedule =====
// C[M][1024] = A[M][1024] * Bt[1024][1024]^T + bias, M=65536.
// 512 thr = 8 waves (wm=wave>>2 in {0,1}, wn=wave&3 in 0..3); per-wave out 128x64.
// LDS 64KB static: dbuf d at d*32768: Ah0@0 Ah1@8K Bh0@16K Bh1@24K.
//   Each half = 128 rows x 32 bf16 (64B row = 4 chunks of 16B).
//   T2 swizzle: LDS[r][c] holds global chunk c ^ ((r>>1)&3) (R4-proven, 0 conflicts).
// Wave wm reads only A-half wm; wave wn reads only B-half wn>>1 -> halves free
// for restage right after their last-reading phase + barrier.
// Per K-step s (dbuf d=s&1), 4 phases (quadrant order 00,01,11,10):
//  P0: read afA(4)+bf0(2); stage Bh0(s+1)->d^1;            bar; lgkm0; 8 MFMA; bar
//  P1: read bf1(2);        stage Bh1(s+1)->d^1;            bar; lgkm0; 8 MFMA; bar
//  P2: read afB(4);                                        bar; lgkm0; 8 MFMA; bar
//  P3: read bf0(2);        stage Ah0,Ah1(s+2)->d;          bar; lgkm0; 8 MFMA;
//      vmcnt(2) [tail: 0]; bar
// Boundary vmcnt(2): newest 2 outstanding = P3's A(s+2); waits Bh1(s+1)+older.
// Every half-tile >=2.5 phases in flight before first use.

__global__ __launch_bounds__(512, 2) void vocab_gemm10_k(
    const bf16_t* __restrict__ A,   // [M][JD] joint bf16
    const bf16_t* __restrict__ Bt,  // [VV][JD] W_out^T bf16
    const float* __restrict__ bias, // [VV]
    float* __restrict__ C) {        // [M][VV]
  __shared__ char smem[65536];
  const int tid  = threadIdx.x;
  const int wave = tid >> 6, lane = tid & 63;
  const int wm = wave >> 2, wn = wave & 3;

  // T1: bijective XCD swizzle (grid = 1024, divisible by 8), n-fastest order.
  const int cpx = gridDim.x >> 3;
  const int b   = blockIdx.x;
  const int lb  = (b & 7) * cpx + (b >> 3);
  const int n0  = (lb & 3) * 256;
  const int m0  = (lb >> 2) * 256;

  // staging geometry: LDS slot r = wave*16 + (lane>>2), c = lane&3 (linear dest)
  const int sr  = wave * 16 + (lane >> 2);
  const int scg = (lane & 3) ^ ((sr >> 1) & 3);  // inverse-swizzled global chunk
  const int ldst = wave * 1024 + lane * 16;      // byte offset within a half
  const bf16_t* gA0 = A  + (size_t)(m0 + sr)       * JD + scg * 8;
  const bf16_t* gA1 = A  + (size_t)(m0 + 128 + sr) * JD + scg * 8;
  const bf16_t* gB0 = Bt + (size_t)(n0 + sr)       * JD + scg * 8;
  const bf16_t* gB1 = Bt + (size_t)(n0 + 128 + sr) * JD + scg * 8;

  // fragment-read geometry
  const int sl = lane & 15, ql = lane >> 4;

  f32x4 acc[8][4] = {};
  bf16x8 af[4], bf[2];
  const int NT = JD / 32;  // 32 K-steps

#define STAGE(D, H, S)                                                        \
  do {                                                                        \
    const bf16_t* g_ = ((H) == 0 ? gA0 : (H) == 1 ? gA1 : (H) == 2 ? gB0 : gB1) + (S) * 32; \
    gl2lds16(g_, smem + (D) * 32768 + (H) * 8192 + ldst);                     \
  } while (0)

#define LOAD_AF(D, QM)                                                        \
  do {                                                                        \
    _Pragma("unroll")                                                         \
    for (int i = 0; i < 4; ++i) {                                             \
      const int lr = (QM) * 64 + i * 16 + sl;                                 \
      af[i] = *(const bf16x8*)(const void*)(                                  \
          smem + (D) * 32768 + wm * 8192 + lr * 64 + ((ql ^ ((lr >> 1) & 3)) * 16)); \
    }                                                                         \
  } while (0)

#define LOAD_BF(D, QN)                                                        \
  do {                                                                        \
    _Pragma("unroll")                                                         \
    for (int jj = 0; jj < 2; ++jj) {                                          \
      const int lr = (wn & 1) * 64 + ((QN) * 2 + jj) * 16 + sl;               \
      bf[jj] = *(const bf16x8*)(const void*)(                                 \
          smem + (D) * 32768 + 16384 + (wn >> 1) * 8192 + lr * 64 +           \
          ((ql ^ ((lr >> 1) & 3)) * 16));                                     \
    }                                                                         \
  } while (0)

#define MFMA_Q(QM, QN)                                                        \
  do {                                                                        \
    __builtin_amdgcn_s_setprio(1);                                            \
    _Pragma("unroll")                                                         \
    for (int i = 0; i < 4; ++i)                                               \
      _Pragma("unroll")                                                       \
      for (int jj = 0; jj < 2; ++jj)                                          \
        acc[(QM) * 4 + i][(QN) * 2 + jj] = __builtin_amdgcn_mfma_f32_16x16x32_bf16( \
            af[i], bf[jj], acc[(QM) * 4 + i][(QN) * 2 + jj], 0, 0, 0);        \
    __builtin_amdgcn_s_setprio(0);                                            \
  } while (0)

#define BAR1()                                                                \
  do {                                                                        \
    __builtin_amdgcn_s_barrier();                                             \
    asm volatile("s_waitcnt lgkmcnt(0)" ::: "memory");                        \
    __builtin_amdgcn_sched_barrier(0);                                        \
  } while (0)

#define BAR2()                                                                \
  do {                                                                        \
    __builtin_amdgcn_s_barrier();                                             \
    __builtin_amdgcn_sched_barrier(0);                                        \
  } while (0)

#define STEP(D, S)                                                            \
  do {                                                                        \
    const int s_ = (S);                                                       \
    /* P0: Q(0,0) */                                                          \
    LOAD_AF(D, 0); LOAD_BF(D, 0);                                             \
    if (s_ + 1 < NT) STAGE((D) ^ 1, 2, s_ + 1);                               \
    BAR1(); MFMA_Q(0, 0); BAR2();                                             \
    /* P1: Q(0,1) */                                                          \
    LOAD_BF(D, 1);                                                            \
    if (s_ + 1 < NT) STAGE((D) ^ 1, 3, s_ + 1);                               \
    BAR1(); MFMA_Q(0, 1); BAR2();                                             \
    /* P2: Q(1,1) */                                                          \
    LOAD_AF(D, 1);                                                            \
    BAR1(); MFMA_Q(1, 1); BAR2();                                             \
    /* P3: Q(1,0) */                                                          \
    LOAD_BF(D, 0);                                                            \
    if (s_ + 2 < NT) { STAGE(D, 0, s_ + 2); STAGE(D, 1, s_ + 2); }            \
    BAR1(); MFMA_Q(1, 0);                                                     \
    if (s_ + 1 < NT) {                                                        \
      if (s_ + 2 < NT) asm volatile("s_waitcnt vmcnt(2)" ::: "memory");       \
      else             asm volatile("s_waitcnt vmcnt(0)" ::: "memory");       \
      BAR2();                                                                 \
    }                                                                         \
  } while (0)

  // ---- prologue: step0 all 4 halves -> dbuf0; step1 A-halves -> dbuf1 ----
  STAGE(0, 0, 0); STAGE(0, 1, 0); STAGE(0, 2, 0); STAGE(0, 3, 0);
  STAGE(1, 0, 1); STAGE(1, 1, 1);
  asm volatile("s_waitcnt vmcnt(2)" ::: "memory");  // step0 landed; step1 A in flight
  __builtin_amdgcn_s_barrier();
  __builtin_amdgcn_sched_barrier(0);

  for (int it = 0; it < NT / 2; ++it) {
    STEP(0, 2 * it);
    STEP(1, 2 * it + 1);
  }

#undef STAGE
#undef LOAD_AF
#undef LOAD_BF
#undef MFMA_Q
#undef BAR1
#undef BAR2
#undef STEP

  // ---- epilogue (bias here so the K-loop has no stray VMEM) ----
  float bv[4];
#pragma unroll
  for (int j = 0; j < 4; ++j) bv[j] = bias[n0 + wn * 64 + j * 16 + (lane & 15)];
#pragma unroll
  for (int i = 0; i < 8; ++i) {
    const int row = m0 + wm * 128 + i * 16 + ((lane >> 4) << 2);
#pragma unroll
    for (int j = 0; j < 4; ++j) {
      const int col = n0 + wn * 64 + j * 16 + (lane & 15);
#pragma unroll
      for (int rr = 0; rr < 4; ++rr)
        C[(size_t)(row + rr) * VV + col] = acc[i][j][rr] + bv[j];
    }
  }
}

extern "C" void kernel_launch(void* const* d_in, const int* in_sizes, int n_in,
                              void* d_out, int out_size, void* d_ws, size_t ws_size,
                              hipStream_t stream) {
  const float* enc    = (const float*)d_in[0];  // [4,256,512]
  const float* pred   = (const float*)d_in[1];  // [4,64,512]
  const float* W_enc  = (const float*)d_in[2];  // [512,1024]
  const float* b_enc  = (const float*)d_in[3];  // [1024]
  const float* W_pred = (const float*)d_in[4];  // [512,1024]
  const float* b_pred = (const float*)d_in[5];  // [1024]
  const float* W_out  = (const float*)d_in[6];  // [1024,1024]
  const float* b_out  = (const float*)d_in[7];  // [1024]
  float* out = (float*)d_out;                   // [4,256,64,1024]

  char* ws = (char*)d_ws;
  bf16_t* encb   = (bf16_t*)(ws + 0x000000);  // 1 MB   [1024][512]
  bf16_t* predb  = (bf16_t*)(ws + 0x100000);  // 256 KB [256][512]
  bf16_t* WtE    = (bf16_t*)(ws + 0x140000);  // 1 MB   [1024][512]
  bf16_t* WtP    = (bf16_t*)(ws + 0x240000);  // 1 MB   [1024][512]
  bf16_t* WtO    = (bf16_t*)(ws + 0x340000);  // 2 MB   [1024][1024]
  float*  enc_o  = (float*) (ws + 0x540000);  // 4 MB   [1024][1024]
  float*  pred_o = (float*) (ws + 0x940000);  // 1 MB   [256][1024]
  bf16_t* joint  = (bf16_t*)(ws + 0xA40000);  // 128 MB [65536][1024]

  // 1) prep: cvt enc/pred + transpose all three weights
  prep_k<<<2688, 256, 0, stream>>>(enc, pred, encb, predb, W_enc, WtE, W_pred, WtP, W_out, WtO);
  // 2) both projections (bias folded)
  proj2_k<<<80, 256, 0, stream>>>(encb, predb, WtE, WtP, b_enc, b_pred, enc_o, pred_o);
  // 3) tanh materialize (bf16 joint)
  tanh_mat_k<<<(B_*T_*U_) * JD / (8 * 256), 256, 0, stream>>>(enc_o, pred_o, joint);
  // 4) fine-phase vocab GEMM
  vocab_gemm10_k<<<dim3(((B_*T_*U_) / 256) * (VV / 256)), 512, 0, stream>>>(
      joint, WtO, b_out, out);
}

// Round 6
// 427.054 us; speedup vs baseline: 1.1631x; 1.0206x over previous
//
#include <hip/hip_runtime.h>
#include <hip/hip_bf16.h>

// Transducer joint: logits[b,t,u,:] = tanh(enc_out[b,t,:] + pred_out[b,u,:]) @ W_out + b_out
// B=4 T=256 U=64 D=512 J=1024 V=1024.
// R4: 256x256/BK=32 gl2lds 2-phase: 184us vocab, MfmaUtil 31%.
// R5: tanh-fusion REGRESSED (tanh serialized between barriers). Reverted.
// R6: reg-staged depth-2 coarse: 193us. Staging mechanism irrelevant.
// R7: 4-phase fine-interleave BK=32 @64KB: vocab ~166us (+16%). Confirmed lever.
// R8: BK=64 m201-faithful 8-phase/2-tiles @128KB DYNAMIC LDS (16 MFMA/phase,
//     half the barrier overhead per FLOP). hipFuncSetAttribute is CHECKED;
//     on failure we fall back to the proven R7 kernel (worst case = R7 perf).
//     Swizzle for 128B rows: key = r&7 over 8 chunks (bank = (c*4)%32 is
//     row-invariant at this row stride). Staging rotation P0:A1(t+1)
//     P1:B0(t+1) P2:B1(t+1) P3:A0(t+2); boundary vmcnt(2), never 0 mid-loop.

typedef __bf16 bf16x8 __attribute__((ext_vector_type(8)));
typedef float f32x4 __attribute__((ext_vector_type(4)));
typedef unsigned int u32x4 __attribute__((ext_vector_type(4)));
using bf16_t = __hip_bfloat16;

#define B_ 4
#define T_ 256
#define U_ 64
#define DE 512
#define JD 1024
#define VV 1024

// async 16B/lane global->LDS. LDS dest is wave-uniform base + lane*16 (m104/m108).
__device__ __forceinline__ void gl2lds16(const void* g, void* l) {
  __builtin_amdgcn_global_load_lds(
      (__attribute__((address_space(1))) void*)(g),
      (__attribute__((address_space(3))) void*)(l), 16, 0, 0);
}

__device__ __forceinline__ float fast_tanh(float x) {
  float xx = fminf(fmaxf(x, -30.f), 30.f);
  float e = __expf(2.f * xx);
  return 1.f - 2.f * __builtin_amdgcn_rcpf(e + 1.f);
}

// ===================== prep: cvt enc/pred + 3 weight transposes ============
__device__ __forceinline__ void transpose_body(const float* __restrict__ src,
                                               bf16_t* __restrict__ dst,
                                               int K, int N, int bx, int by, int tid,
                                               float (*tile)[33]) {
  const int nt = bx * 32, kt = by * 32;
  const int tx = tid & 31, ty = tid >> 5;  // 32 x 8
#pragma unroll
  for (int i = 0; i < 4; ++i)
    tile[ty + i * 8][tx] = src[(size_t)(kt + ty + i * 8) * N + nt + tx];
  __syncthreads();
#pragma unroll
  for (int i = 0; i < 4; ++i)
    dst[(size_t)(nt + ty + i * 8) * K + kt + tx] = __float2bfloat16(tile[tx][ty + i * 8]);
}

__global__ __launch_bounds__(256) void prep_k(
    const float* __restrict__ enc, const float* __restrict__ pred,
    bf16_t* __restrict__ encb, bf16_t* __restrict__ predb,
    const float* __restrict__ W_enc, bf16_t* __restrict__ WtE,
    const float* __restrict__ W_pred, bf16_t* __restrict__ WtP,
    const float* __restrict__ W_out, bf16_t* __restrict__ WtO) {
  __shared__ float tile[32][33];
  const int bid = blockIdx.x, tid = threadIdx.x;
  if (bid < 640) {
    size_t i = ((size_t)bid * 256 + tid) * 4;
    const float* src;
    bf16_t* dst;
    if (i < (size_t)B_ * T_ * DE) { src = enc; dst = encb; }
    else { i -= (size_t)B_ * T_ * DE; src = pred; dst = predb; }
    f32x4 v = *(const f32x4*)(src + i);
    bf16_t o[4];
#pragma unroll
    for (int z = 0; z < 4; ++z) o[z] = __float2bfloat16(v[z]);
    *(unsigned long long*)(dst + i) = *(unsigned long long*)o;
  } else if (bid < 1152) {
    const int lb = bid - 640;
    transpose_body(W_enc, WtE, DE, JD, lb & 31, lb >> 5, tid, tile);
  } else if (bid < 1664) {
    const int lb = bid - 1152;
    transpose_body(W_pred, WtP, DE, JD, lb & 31, lb >> 5, tid, tile);
  } else {
    const int lb = bid - 1664;
    transpose_body(W_out, WtO, JD, VV, lb & 31, lb >> 5, tid, tile);
  }
}

// ============== proj2: both projections, m97-style 128x128/BK=32 ===========
__device__ __forceinline__ void proj_body(const bf16_t* __restrict__ A,
                                          const bf16_t* __restrict__ Bt,
                                          const float* __restrict__ bias,
                                          float* __restrict__ C,
                                          int m0, int n0, int N, int K) {
  __shared__ bf16_t sA[128 * 32];
  __shared__ bf16_t sB[128 * 32];
  const int tid = threadIdx.x;
  const int wave = tid >> 6, lane = tid & 63;
  const int wm = wave >> 1, wn = wave & 1;

  f32x4 acc[4][4] = {};

  for (int k0 = 0; k0 < K; k0 += 32) {
    __syncthreads();
#pragma unroll
    for (int r = 0; r < 2; ++r) {
      const int base = (wave + 4 * r) * 1024;
      const int row  = (base >> 6) + (lane >> 2);
      const int kel  = (lane & 3) * 8;
      gl2lds16(A  + (size_t)(m0 + row) * K + k0 + kel, (char*)sA + base);
      gl2lds16(Bt + (size_t)(n0 + row) * K + k0 + kel, (char*)sB + base);
    }
    __syncthreads();
    bf16x8 af[4], bfr[4];
    const int kq = (lane >> 4) * 8;
#pragma unroll
    for (int i = 0; i < 4; ++i) {
      af[i]  = *(const bf16x8*)(const void*)(sA + (wm * 64 + i * 16 + (lane & 15)) * 32 + kq);
      bfr[i] = *(const bf16x8*)(const void*)(sB + (wn * 64 + i * 16 + (lane & 15)) * 32 + kq);
    }
#pragma unroll
    for (int i = 0; i < 4; ++i)
#pragma unroll
      for (int j = 0; j < 4; ++j)
        acc[i][j] = __builtin_amdgcn_mfma_f32_16x16x32_bf16(af[i], bfr[j], acc[i][j], 0, 0, 0);
  }

  float bv[4];
#pragma unroll
  for (int j = 0; j < 4; ++j) bv[j] = bias[n0 + wn * 64 + j * 16 + (lane & 15)];
#pragma unroll
  for (int i = 0; i < 4; ++i) {
    const int row = m0 + wm * 64 + i * 16 + ((lane >> 4) << 2);
#pragma unroll
    for (int j = 0; j < 4; ++j) {
      const int col = n0 + wn * 64 + j * 16 + (lane & 15);
#pragma unroll
      for (int rr = 0; rr < 4; ++rr)
        C[(size_t)(row + rr) * N + col] = acc[i][j][rr] + bv[j];
    }
  }
}

__global__ __launch_bounds__(256) void proj2_k(
    const bf16_t* __restrict__ encb, const bf16_t* __restrict__ predb,
    const bf16_t* __restrict__ WtE, const bf16_t* __restrict__ WtP,
    const float* __restrict__ b_enc, const float* __restrict__ b_pred,
    float* __restrict__ enc_o, float* __restrict__ pred_o) {
  int bid = blockIdx.x;
  if (bid < 64) {
    proj_body(encb, WtE, b_enc, enc_o, (bid >> 3) * 128, (bid & 7) * 128, JD, DE);
  } else {
    bid -= 64;
    proj_body(predb, WtP, b_pred, pred_o, (bid >> 3) * 128, (bid & 7) * 128, JD, DE);
  }
}

// ------------- tanh materialize: joint[m][j] = tanh(enc_o + pred_o), bf16 ---
__global__ __launch_bounds__(256) void tanh_mat_k(
    const float* __restrict__ enc_o,   // [B*T][JD]
    const float* __restrict__ pred_o,  // [B*U][JD]
    bf16_t* __restrict__ joint) {      // [B*T*U][JD]
  size_t i = ((size_t)blockIdx.x * 256 + threadIdx.x) * 8;
  const int m = (int)(i >> 10);
  const int j = (int)(i & 1023);
  const int enc_row  = m >> 6;
  const int pred_row = ((m >> 14) << 6) | (m & 63);
  const f32x4* pe = (const f32x4*)(enc_o  + (size_t)enc_row  * JD + j);
  const f32x4* pp = (const f32x4*)(pred_o + (size_t)pred_row * JD + j);
  bf16_t vals[8];
#pragma unroll
  for (int q = 0; q < 2; ++q) {
    f32x4 e = pe[q], p = pp[q];
#pragma unroll
    for (int z = 0; z < 4; ++z)
      vals[q * 4 + z] = __float2bfloat16(fast_tanh(e[z] + p[z]));
  }
  *(u32x4*)(void*)(joint + i) = *(const u32x4*)(const void*)vals;
}

// ====== R7 vocab GEMM (FALLBACK): 256x256/BK=32, 4-phase, 64KB static ======
__global__ __launch_bounds__(512, 2) void vocab_gemm10_k(
    const bf16_t* __restrict__ A, const bf16_t* __restrict__ Bt,
    const float* __restrict__ bias, float* __restrict__ C) {
  __shared__ char smem[65536];
  const int tid  = threadIdx.x;
  const int wave = tid >> 6, lane = tid & 63;
  const int wm = wave >> 2, wn = wave & 3;

  const int cpx = gridDim.x >> 3;
  const int b   = blockIdx.x;
  const int lb  = (b & 7) * cpx + (b >> 3);
  const int n0  = (lb & 3) * 256;
  const int m0  = (lb >> 2) * 256;

  const int sr  = wave * 16 + (lane >> 2);
  const int scg = (lane & 3) ^ ((sr >> 1) & 3);
  const int ldst = wave * 1024 + lane * 16;
  const bf16_t* gA0 = A  + (size_t)(m0 + sr)       * JD + scg * 8;
  const bf16_t* gA1 = A  + (size_t)(m0 + 128 + sr) * JD + scg * 8;
  const bf16_t* gB0 = Bt + (size_t)(n0 + sr)       * JD + scg * 8;
  const bf16_t* gB1 = Bt + (size_t)(n0 + 128 + sr) * JD + scg * 8;

  const int sl = lane & 15, ql = lane >> 4;

  f32x4 acc[8][4] = {};
  bf16x8 af[4], bf[2];
  const int NT = JD / 32;

#define STAGE(D, H, S)                                                        \
  do {                                                                        \
    const bf16_t* g_ = ((H) == 0 ? gA0 : (H) == 1 ? gA1 : (H) == 2 ? gB0 : gB1) + (S) * 32; \
    gl2lds16(g_, smem + (D) * 32768 + (H) * 8192 + ldst);                     \
  } while (0)

#define LOAD_AF(D, QM)                                                        \
  do {                                                                        \
    _Pragma("unroll")                                                         \
    for (int i = 0; i < 4; ++i) {                                             \
      const int lr = (QM) * 64 + i * 16 + sl;                                 \
      af[i] = *(const bf16x8*)(const void*)(                                  \
          smem + (D) * 32768 + wm * 8192 + lr * 64 + ((ql ^ ((lr >> 1) & 3)) * 16)); \
    }                                                                         \
  } while (0)

#define LOAD_BF(D, QN)                                                        \
  do {                                                                        \
    _Pragma("unroll")                                                         \
    for (int jj = 0; jj < 2; ++jj) {                                          \
      const int lr = (wn & 1) * 64 + ((QN) * 2 + jj) * 16 + sl;               \
      bf[jj] = *(const bf16x8*)(const void*)(                                 \
          smem + (D) * 32768 + 16384 + (wn >> 1) * 8192 + lr * 64 +           \
          ((ql ^ ((lr >> 1) & 3)) * 16));                                     \
    }                                                                         \
  } while (0)

#define MFMA_Q(QM, QN)                                                        \
  do {                                                                        \
    __builtin_amdgcn_s_setprio(1);                                            \
    _Pragma("unroll")                                                         \
    for (int i = 0; i < 4; ++i)                                               \
      _Pragma("unroll")                                                       \
      for (int jj = 0; jj < 2; ++jj)                                          \
        acc[(QM) * 4 + i][(QN) * 2 + jj] = __builtin_amdgcn_mfma_f32_16x16x32_bf16( \
            af[i], bf[jj], acc[(QM) * 4 + i][(QN) * 2 + jj], 0, 0, 0);        \
    __builtin_amdgcn_s_setprio(0);                                            \
  } while (0)

#define BAR1()                                                                \
  do {                                                                        \
    __builtin_amdgcn_s_barrier();                                             \
    asm volatile("s_waitcnt lgkmcnt(0)" ::: "memory");                        \
    __builtin_amdgcn_sched_barrier(0);                                        \
  } while (0)

#define BAR2()                                                                \
  do {                                                                        \
    __builtin_amdgcn_s_barrier();                                             \
    __builtin_amdgcn_sched_barrier(0);                                        \
  } while (0)

#define STEP(D, S)                                                            \
  do {                                                                        \
    const int s_ = (S);                                                       \
    LOAD_AF(D, 0); LOAD_BF(D, 0);                                             \
    if (s_ + 1 < NT) STAGE((D) ^ 1, 2, s_ + 1);                               \
    BAR1(); MFMA_Q(0, 0); BAR2();                                             \
    LOAD_BF(D, 1);                                                            \
    if (s_ + 1 < NT) STAGE((D) ^ 1, 3, s_ + 1);                               \
    BAR1(); MFMA_Q(0, 1); BAR2();                                             \
    LOAD_AF(D, 1);                                                            \
    BAR1(); MFMA_Q(1, 1); BAR2();                                             \
    LOAD_BF(D, 0);                                                            \
    if (s_ + 2 < NT) { STAGE(D, 0, s_ + 2); STAGE(D, 1, s_ + 2); }            \
    BAR1(); MFMA_Q(1, 0);                                                     \
    if (s_ + 1 < NT) {                                                        \
      if (s_ + 2 < NT) asm volatile("s_waitcnt vmcnt(2)" ::: "memory");       \
      else             asm volatile("s_waitcnt vmcnt(0)" ::: "memory");       \
      BAR2();                                                                 \
    }                                                                         \
  } while (0)

  STAGE(0, 0, 0); STAGE(0, 1, 0); STAGE(0, 2, 0); STAGE(0, 3, 0);
  STAGE(1, 0, 1); STAGE(1, 1, 1);
  asm volatile("s_waitcnt vmcnt(2)" ::: "memory");
  __builtin_amdgcn_s_barrier();
  __builtin_amdgcn_sched_barrier(0);

  for (int it = 0; it < NT / 2; ++it) {
    STEP(0, 2 * it);
    STEP(1, 2 * it + 1);
  }

#undef STAGE
#undef LOAD_AF
#undef LOAD_BF
#undef MFMA_Q
#undef BAR1
#undef BAR2
#undef STEP

  float bv[4];
#pragma unroll
  for (int j = 0; j < 4; ++j) bv[j] = bias[n0 + wn * 64 + j * 16 + (lane & 15)];
#pragma unroll
  for (int i = 0; i < 8; ++i) {
    const int row = m0 + wm * 128 + i * 16 + ((lane >> 4) << 2);
#pragma unroll
    for (int j = 0; j < 4; ++j) {
      const int col = n0 + wn * 64 + j * 16 + (lane & 15);
#pragma unroll
      for (int rr = 0; rr < 4; ++rr)
        C[(size_t)(row + rr) * VV + col] = acc[i][j][rr] + bv[j];
    }
  }
}

// ====== R8 vocab GEMM: 256x256/BK=64, 4-phase/K-tile, 128KB dynamic LDS ====
// LDS: dbuf d @ d*65536: Ah0@0 Ah1@16K Bh0@32K Bh1@48K. Half = 128 rows x 64
// bf16 (128B row = 8 chunks of 16B). Swizzle: LDS[r][c] holds global chunk
// c ^ (r&7)  (bank = (c*4)%32 is row-invariant at 128B stride -> key r&7
// spreads 16 row-lanes over all 8 chunks, 2/chunk = free).
// Per K-tile t (dbuf D=t&1), quadrants (0,0)(0,1)(1,1)(1,0), 16 MFMA/phase:
//  P0: read af[2][4](qm0, 8) + bf[2][2](qn0, 4); stage A1(t+1); bar;lgkm0; MFMA
//  P1: read bf(qn1, 4);                          stage B0(t+1); bar;lgkm0; MFMA
//  P2: read af(qm1, 8);                          stage B1(t+1); bar;lgkm0; MFMA
//  P3: read bf(qn0, 4);                          stage A0(t+2); bar;lgkm0; MFMA;
//      vmcnt(2) [tail 0]; bar
// Every half-tile >=3 phases in flight; regions staged only after their last
// reader's phase closed (A-halves free after P2, B-halves after tile close).

__global__ __launch_bounds__(512, 2) void vocab_gemm11_k(
    const bf16_t* __restrict__ A,   // [M][JD] joint bf16
    const bf16_t* __restrict__ Bt,  // [VV][JD] W_out^T bf16
    const float* __restrict__ bias, // [VV]
    float* __restrict__ C) {        // [M][VV]
  extern __shared__ char smem[];  // 131072 B
  const int tid  = threadIdx.x;
  const int wave = tid >> 6, lane = tid & 63;
  const int wm = wave >> 2, wn = wave & 3;

  // T1: bijective XCD swizzle (grid = 1024, divisible by 8), n-fastest order.
  const int cpx = gridDim.x >> 3;
  const int b   = blockIdx.x;
  const int lb  = (b & 7) * cpx + (b >> 3);
  const int n0  = (lb & 3) * 256;
  const int m0  = (lb >> 2) * 256;

  // staging geometry: half-tile = 1024 chunks; thread covers idx = {tid, 512+tid}.
  // idx -> row = idx>>3 (r0, r0+64 share r&7), chunk c = tid&7, cg = c ^ (r0&7).
  const int r0  = tid >> 3;
  const int cg  = (tid & 7) ^ (r0 & 7);
  const int stid = tid * 16;  // linear LDS byte offset of load g=0 (g=1: +8192)
  const bf16_t* gA0a = A  + (size_t)(m0 + r0)        * JD + cg * 8;
  const bf16_t* gA0b = A  + (size_t)(m0 + 64 + r0)   * JD + cg * 8;
  const bf16_t* gA1a = A  + (size_t)(m0 + 128 + r0)  * JD + cg * 8;
  const bf16_t* gA1b = A  + (size_t)(m0 + 192 + r0)  * JD + cg * 8;
  const bf16_t* gB0a = Bt + (size_t)(n0 + r0)        * JD + cg * 8;
  const bf16_t* gB0b = Bt + (size_t)(n0 + 64 + r0)   * JD + cg * 8;
  const bf16_t* gB1a = Bt + (size_t)(n0 + 128 + r0)  * JD + cg * 8;
  const bf16_t* gB1b = Bt + (size_t)(n0 + 192 + r0)  * JD + cg * 8;

  const int sl = lane & 15, ql = lane >> 4;

  f32x4 acc[8][4] = {};
  bf16x8 af[2][4], bf[2][2];
  const int NT = JD / 64;  // 16 K-tiles

#define STAGE(H, S)                                                           \
  do {                                                                        \
    char* lb_ = smem + ((S) & 1) * 65536 + (H) * 16384 + stid;                \
    const bf16_t* ga_ = ((H) == 0 ? gA0a : (H) == 1 ? gA1a : (H) == 2 ? gB0a : gB1a) + (S) * 64; \
    const bf16_t* gb_ = ((H) == 0 ? gA0b : (H) == 1 ? gA1b : (H) == 2 ? gB0b : gB1b) + (S) * 64; \
    gl2lds16(ga_, lb_);                                                       \
    gl2lds16(gb_, lb_ + 8192);                                                \
  } while (0)

#define LOAD_AF(D, QM)                                                        \
  do {                                                                        \
    _Pragma("unroll")                                                         \
    for (int ks = 0; ks < 2; ++ks)                                            \
      _Pragma("unroll")                                                       \
      for (int i = 0; i < 4; ++i) {                                           \
        const int lr = (QM) * 64 + i * 16 + sl;                               \
        const int ck = (ks * 4 + ql) ^ (lr & 7);                              \
        af[ks][i] = *(const bf16x8*)(const void*)(                            \
            smem + (D) * 65536 + wm * 16384 + lr * 128 + ck * 16);            \
      }                                                                       \
  } while (0)

#define LOAD_BF(D, QN)                                                        \
  do {                                                                        \
    _Pragma("unroll")                                                         \
    for (int ks = 0; ks < 2; ++ks)                                            \
      _Pragma("unroll")                                                       \
      for (int jj = 0; jj < 2; ++jj) {                                        \
        const int lr = (wn & 1) * 64 + ((QN) * 2 + jj) * 16 + sl;             \
        const int ck = (ks * 4 + ql) ^ (lr & 7);                              \
        bf[ks][jj] = *(const bf16x8*)(const void*)(                           \
            smem + (D) * 65536 + 32768 + (wn >> 1) * 16384 + lr * 128 + ck * 16); \
      }                                                                       \
  } while (0)

#define MFMA_Q(QM, QN)                                                        \
  do {                                                                        \
    __builtin_amdgcn_s_setprio(1);                                            \
    _Pragma("unroll")                                                         \
    for (int ks = 0; ks < 2; ++ks)                                            \
      _Pragma("unroll")                                                       \
      for (int i = 0; i < 4; ++i)                                             \
        _Pragma("unroll")                                                     \
        for (int jj = 0; jj < 2; ++jj)                                        \
          acc[(QM) * 4 + i][(QN) * 2 + jj] = __builtin_amdgcn_mfma_f32_16x16x32_bf16( \
              af[ks][i], bf[ks][jj], acc[(QM) * 4 + i][(QN) * 2 + jj], 0, 0, 0); \
    __builtin_amdgcn_s_setprio(0);                                            \
  } while (0)

#define BARW()                                                                \
  do {                                                                        \
    __builtin_amdgcn_s_barrier();                                             \
    asm volatile("s_waitcnt lgkmcnt(0)" ::: "memory");                        \
    __builtin_amdgcn_sched_barrier(0);                                        \
  } while (0)

#define BARC()                                                                \
  do {                                                                        \
    __builtin_amdgcn_s_barrier();                                             \
    __builtin_amdgcn_sched_barrier(0);                                        \
  } while (0)

#define TILE(D, S)                                                            \
  do {                                                                        \
    const int t_ = (S);                                                       \
    /* P0: Q(0,0); stage A1(t+1) */                                           \
    LOAD_AF(D, 0); LOAD_BF(D, 0);                                             \
    if (t_ + 1 < NT) STAGE(1, t_ + 1);                                        \
    BARW(); MFMA_Q(0, 0); BARC();                                             \
    /* P1: Q(0,1); stage B0(t+1) */                                           \
    LOAD_BF(D, 1);                                                            \
    if (t_ + 1 < NT) STAGE(2, t_ + 1);                                        \
    BARW(); MFMA_Q(0, 1); BARC();                                             \
    /* P2: Q(1,1); stage B1(t+1) */                                           \
    LOAD_AF(D, 1);                                                            \
    if (t_ + 1 < NT) STAGE(3, t_ + 1);                                        \
    BARW(); MFMA_Q(1, 1); BARC();                                             \
    /* P3: Q(1,0); stage A0(t+2); boundary counted vmcnt */                   \
    LOAD_BF(D, 0);                                                            \
    if (t_ + 2 < NT) STAGE(0, t_ + 2);                                        \
    BARW(); MFMA_Q(1, 0);                                                     \
    if (t_ + 1 < NT) {                                                        \
      if (t_ + 2 < NT) asm volatile("s_waitcnt vmcnt(2)" ::: "memory");       \
      else             asm volatile("s_waitcnt vmcnt(0)" ::: "memory");       \
      BARC();                                                                 \
    }                                                                         \
  } while (0)

  // prologue: all of tile0 + A0(1); vmcnt(2) leaves A0(1) in flight.
  STAGE(0, 0); STAGE(1, 0); STAGE(2, 0); STAGE(3, 0);
  STAGE(0, 1);
  asm volatile("s_waitcnt vmcnt(2)" ::: "memory");
  __builtin_amdgcn_s_barrier();
  __builtin_amdgcn_sched_barrier(0);

  for (int it = 0; it < NT / 2; ++it) {
    TILE(0, 2 * it);
    TILE(1, 2 * it + 1);
  }

#undef STAGE
#undef LOAD_AF
#undef LOAD_BF
#undef MFMA_Q
#undef BARW
#undef BARC
#undef TILE

  // ---- epilogue (bias here so the K-loop has no stray VMEM) ----
  float bv[4];
#pragma unroll
  for (int j = 0; j < 4; ++j) bv[j] = bias[n0 + wn * 64 + j * 16 + (lane & 15)];
#pragma unroll
  for (int i = 0; i < 8; ++i) {
    const int row = m0 + wm * 128 + i * 16 + ((lane >> 4) << 2);
#pragma unroll
    for (int j = 0; j < 4; ++j) {
      const int col = n0 + wn * 64 + j * 16 + (lane & 15);
#pragma unroll
      for (int rr = 0; rr < 4; ++rr)
        C[(size_t)(row + rr) * VV + col] = acc[i][j][rr] + bv[j];
    }
  }
}

extern "C" void kernel_launch(void* const* d_in, const int* in_sizes, int n_in,
                              void* d_out, int out_size, void* d_ws, size_t ws_size,
                              hipStream_t stream) {
  const float* enc    = (const float*)d_in[0];  // [4,256,512]
  const float* pred   = (const float*)d_in[1];  // [4,64,512]
  const float* W_enc  = (const float*)d_in[2];  // [512,1024]
  const float* b_enc  = (const float*)d_in[3];  // [1024]
  const float* W_pred = (const float*)d_in[4];  // [512,1024]
  const float* b_pred = (const float*)d_in[5];  // [1024]
  const float* W_out  = (const float*)d_in[6];  // [1024,1024]
  const float* b_out  = (const float*)d_in[7];  // [1024]
  float* out = (float*)d_out;                   // [4,256,64,1024]

  char* ws = (char*)d_ws;
  bf16_t* encb   = (bf16_t*)(ws + 0x000000);  // 1 MB   [1024][512]
  bf16_t* predb  = (bf16_t*)(ws + 0x100000);  // 256 KB [256][512]
  bf16_t* WtE    = (bf16_t*)(ws + 0x140000);  // 1 MB   [1024][512]
  bf16_t* WtP    = (bf16_t*)(ws + 0x240000);  // 1 MB   [1024][512]
  bf16_t* WtO    = (bf16_t*)(ws + 0x340000);  // 2 MB   [1024][1024]
  float*  enc_o  = (float*) (ws + 0x540000);  // 4 MB   [1024][1024]
  float*  pred_o = (float*) (ws + 0x940000);  // 1 MB   [256][1024]
  bf16_t* joint  = (bf16_t*)(ws + 0xA40000);  // 128 MB [65536][1024]

  // 1) prep: cvt enc/pred + transpose all three weights
  prep_k<<<2688, 256, 0, stream>>>(enc, pred, encb, predb, W_enc, WtE, W_pred, WtP, W_out, WtO);
  // 2) both projections (bias folded)
  proj2_k<<<80, 256, 0, stream>>>(encb, predb, WtE, WtP, b_enc, b_pred, enc_o, pred_o);
  // 3) tanh materialize (bf16 joint)
  tanh_mat_k<<<(B_*T_*U_) * JD / (8 * 256), 256, 0, stream>>>(enc_o, pred_o, joint);
  // 4) vocab GEMM: BK=64/128KB if dynamic-LDS attribute succeeds, else R7 kernel
  static int big_lds = -1;
  if (big_lds < 0) {
    big_lds = (hipFuncSetAttribute(reinterpret_cast<const void*>(vocab_gemm11_k),
                                   hipFuncAttributeMaxDynamicSharedMemorySize,
                                   131072) == hipSuccess) ? 1 : 0;
  }
  if (big_lds == 1) {
    vocab_gemm11_k<<<dim3(((B_*T_*U_) / 256) * (VV / 256)), 512, 131072, stream>>>(
        joint, WtO, b_out, out);
  } else {
    vocab_gemm10_k<<<dim3(((B_*T_*U_) / 256) * (VV / 256)), 512, 0, stream>>>(
        joint, WtO, b_out, out);
  }
}